// Round 1
// baseline (719.720 us; speedup 1.0000x reference)
//
#include <hip/hip_runtime.h>

#define NLOC 12
#define F_DIM 512
#define H_DIM 256

typedef float f4 __attribute__((ext_vector_type(4)));
typedef _Float16 half4 __attribute__((ext_vector_type(4)));
typedef _Float16 half8 __attribute__((ext_vector_type(8)));

// workspace layout (bytes)
#define OFF_W1   0ul
#define OFF_W2   (OFF_W1 + 512ul*512*2)          // W1: [512][512] f16
#define OFF_C1   (OFF_W2 + 512ul*1024*2)         // W2: [512][1024] f16
#define OFF_CVEC (OFF_C1 + 2048ul)               // c1: [512] f32
#define OFF_ACAT (OFF_CVEC + 2048ul)             // cvec: [512] f32
#define OFF_BASE (OFF_ACAT + 16384ul*1024*2)     // Acat: [B][1024] f16 (pooled | g)
// base: [B][512] f16  (lfm + g)

// ---------------------------------------------------------------------------
// Precompute W1[f,f'] = sum_h Wk[f,h] Wq[f',h]   (mode 0)
//            W2[f,j]  = sum_h Wf[h,f] Wv[j,h]            (mode 1, cols 0..511)
//            W2[f,512+j] = S * sum_h Wf[256+h,f] Wv[j,h] (mode 2)
// ---------------------------------------------------------------------------
__global__ void __launch_bounds__(256) precompute_w(
    const float* __restrict__ Wq, const float* __restrict__ Wk,
    const float* __restrict__ Wv, const float* __restrict__ Wf,
    const float* __restrict__ wdr,
    _Float16* __restrict__ W1, _Float16* __restrict__ W2)
{
    __shared__ float X[32][264];
    __shared__ float Y[32][264];
    const int mode = blockIdx.z;
    const int f0 = blockIdx.x * 32;
    const int j0 = blockIdx.y * 32;
    const int t = threadIdx.x;

    {
        const int r = t >> 3, cb = (t & 7) * 32;
        const float* ysrc = ((mode == 0) ? Wq : Wv) + (j0 + r) * H_DIM + cb;
#pragma unroll
        for (int u = 0; u < 32; u += 4)
            *(f4*)&Y[r][cb + u] = *(const f4*)(ysrc + u);
        if (mode == 0) {
            const float* xsrc = Wk + (f0 + r) * H_DIM + cb;
#pragma unroll
            for (int u = 0; u < 32; u += 4)
                *(f4*)&X[r][cb + u] = *(const f4*)(xsrc + u);
        }
    }
    if (mode != 0) {
        const int h = t;                       // 0..255
        const int hoff = (mode == 2) ? H_DIM : 0;
        const float* xsrc = Wf + (long)(h + hoff) * F_DIM + f0;
        f4 v[8];
#pragma unroll
        for (int u = 0; u < 8; ++u) v[u] = *(const f4*)(xsrc + u * 4);
#pragma unroll
        for (int r = 0; r < 32; ++r) X[r][h] = v[r >> 2][r & 3];
    }
    __syncthreads();

    const int fy = t >> 4, jx = t & 15;
    float a00 = 0.f, a01 = 0.f, a10 = 0.f, a11 = 0.f;
#pragma unroll 8
    for (int h = 0; h < H_DIM; ++h) {
        float x0 = X[fy][h], x1 = X[fy + 16][h];
        float y0 = Y[jx][h], y1 = Y[jx + 16][h];
        a00 += x0 * y0; a01 += x0 * y1; a10 += x1 * y0; a11 += x1 * y1;
    }
    if (mode == 2) {
        float S = 0.f;
#pragma unroll
        for (int k = 0; k < NLOC; ++k) S += wdr[k];
        a00 *= S; a01 *= S; a10 *= S; a11 *= S;
    }
    if (mode == 0) {
        W1[(f0 + fy) * F_DIM + (j0 + jx)]             = (_Float16)a00;
        W1[(f0 + fy) * F_DIM + (j0 + jx + 16)]        = (_Float16)a01;
        W1[(f0 + fy + 16) * F_DIM + (j0 + jx)]        = (_Float16)a10;
        W1[(f0 + fy + 16) * F_DIM + (j0 + jx + 16)]   = (_Float16)a11;
    } else {
        const long co = (mode == 2) ? F_DIM : 0;
        W2[(long)(f0 + fy) * 1024 + co + (j0 + jx)]           = (_Float16)a00;
        W2[(long)(f0 + fy) * 1024 + co + (j0 + jx + 16)]      = (_Float16)a01;
        W2[(long)(f0 + fy + 16) * 1024 + co + (j0 + jx)]      = (_Float16)a10;
        W2[(long)(f0 + fy + 16) * 1024 + co + (j0 + jx + 16)] = (_Float16)a11;
    }
}

// ---------------------------------------------------------------------------
// c1[f]   = sum_h bq[h] Wk[f,h]
// cvec[f] = bv@Wf_top[:,f] + S*(bv@Wf_bot[:,f]) + b_dr*sum(Wf_bot[:,f]) + bf[f]
// ---------------------------------------------------------------------------
__global__ void __launch_bounds__(256) cvec_kernel(
    const float* __restrict__ Wk, const float* __restrict__ Wf,
    const float* __restrict__ bq, const float* __restrict__ bv,
    const float* __restrict__ wdr, const float* __restrict__ bdr,
    const float* __restrict__ bfv,
    float* __restrict__ c1, float* __restrict__ cvec)
{
    const int f = blockIdx.x * 256 + threadIdx.x;   // 0..511
    f4 a = {0.f, 0.f, 0.f, 0.f};
    const f4* wk4 = (const f4*)(Wk + (long)f * H_DIM);
    const f4* bq4 = (const f4*)bq;
#pragma unroll 4
    for (int h4 = 0; h4 < H_DIM / 4; ++h4) a += wk4[h4] * bq4[h4];
    c1[f] = a[0] + a[1] + a[2] + a[3];

    float s1 = 0.f, s2 = 0.f, s3 = 0.f;
#pragma unroll 4
    for (int h = 0; h < H_DIM; ++h) {
        float w1v = Wf[h * F_DIM + f];
        float w2v = Wf[(H_DIM + h) * F_DIM + f];
        float bvh = bv[h];
        s1 += bvh * w1v; s2 += bvh * w2v; s3 += w2v;
    }
    float S = 0.f;
#pragma unroll
    for (int k = 0; k < NLOC; ++k) S += wdr[k];
    cvec[f] = s1 + S * s2 + bdr[0] * s3 + bfv[f];
}

// ---------------------------------------------------------------------------
// K1: fused  (g->f16) + (t = g@W1^T + c1) + local pass.
// v2: barrier-free phase-1 k-loop — B-fragments loaded directly from W1
//     (L2-resident, 512 KB) as half8; Bs staging + 126 barriers removed.
//     Acat g-half written during staging (values already in f16 regs).
// LDS: G[32][520] + T[32][520] = 66.5 KB -> 2 blocks/CU. Grid 512 blocks.
// ---------------------------------------------------------------------------
__global__ void __launch_bounds__(256, 2) fused_local(
    const float* __restrict__ g, const float* __restrict__ loc,
    const _Float16* __restrict__ W1, const float* __restrict__ c1,
    const float* __restrict__ wdr, const float* __restrict__ bdr,
    _Float16* __restrict__ Acat, _Float16* __restrict__ base)
{
    __shared__ _Float16 G[32][520];
    __shared__ _Float16 T[32][520];
    const int tid = threadIdx.x;
    const int lane = tid & 63;
    const int wave = tid >> 6;
    const int quad = lane >> 4;
    const int l16 = lane & 15;
    const long m0 = (long)blockIdx.x * 32;

    // ---- stage G (f32 -> f16), coalesced; also emit Acat's g-half here
    {
        const int r = tid >> 3;          // 0..31
        const int cb = (tid & 7) * 8;
#pragma unroll
        for (int u = 0; u < 512; u += 64) {
            const float* src = g + (m0 + r) * F_DIM + cb + u;
            f4 v0 = *(const f4*)(src);
            f4 v1 = *(const f4*)(src + 4);
            half8 hv;
#pragma unroll
            for (int j = 0; j < 4; ++j) { hv[j] = (_Float16)v0[j]; hv[4 + j] = (_Float16)v1[j]; }
            *(half8*)&G[r][cb + u] = hv;
            *(half8*)(Acat + (m0 + r) * 1024 + 512 + cb + u) = hv;
        }
    }
    __syncthreads();

    // ---- phase 1: T = G @ W1^T + c1.  No barriers in the k-loop:
    // b-frags come straight from W1 (L2 hit), a-frags from G in LDS.
    const int wn1 = wave * 32;
    for (int nt = 0; nt < 4; ++nt) {
        const int n0 = nt * 128;
        const _Float16* wb0 = W1 + (long)(n0 + wn1 + l16) * F_DIM + quad * 8;
        const _Float16* wb1 = wb0 + 16 * F_DIM;
        f4 acc[2][2] = {{{0.f,0.f,0.f,0.f},{0.f,0.f,0.f,0.f}},
                        {{0.f,0.f,0.f,0.f},{0.f,0.f,0.f,0.f}}};
#pragma unroll
        for (int k0 = 0; k0 < 512; k0 += 32) {
            half8 b0 = *(const half8*)(wb0 + k0);
            half8 b1 = *(const half8*)(wb1 + k0);
            half8 a0 = *(const half8*)&G[l16][k0 + quad * 8];
            half8 a1 = *(const half8*)&G[16 + l16][k0 + quad * 8];
            acc[0][0] = __builtin_amdgcn_mfma_f32_16x16x32_f16(a0, b0, acc[0][0], 0, 0, 0);
            acc[0][1] = __builtin_amdgcn_mfma_f32_16x16x32_f16(a0, b1, acc[0][1], 0, 0, 0);
            acc[1][0] = __builtin_amdgcn_mfma_f32_16x16x32_f16(a1, b0, acc[1][0], 0, 0, 0);
            acc[1][1] = __builtin_amdgcn_mfma_f32_16x16x32_f16(a1, b1, acc[1][1], 0, 0, 0);
        }
#pragma unroll
        for (int ni = 0; ni < 2; ++ni) {
            const int col = n0 + wn1 + ni * 16 + l16;
            const float cv = c1[col];
#pragma unroll
            for (int mi = 0; mi < 2; ++mi)
#pragma unroll
                for (int i = 0; i < 4; ++i)
                    T[mi * 16 + quad * 4 + i][col] = (_Float16)(acc[mi][ni][i] + cv);
        }
    }
    __syncthreads();

    // ---- phase 2: local pass, 8 rows per wave, t & g served from LDS
    const int c0 = lane * 4;
    const int c1i = 256 + lane * 4;
    const float bd = bdr[0];
    float wv[NLOC];
#pragma unroll
    for (int k = 0; k < NLOC; ++k) wv[k] = wdr[k];

    for (int rr = 0; rr < 8; ++rr) {
        const int bl = wave * 8 + rr;
        const long b = m0 + bl;
        const float* lb = loc + b * (NLOC * F_DIM);

        f4 la[NLOC], lbv[NLOC];
#pragma unroll
        for (int k = 0; k < NLOC; ++k) {
            la[k]  = *(const f4*)(lb + k * F_DIM + c0);
            lbv[k] = *(const f4*)(lb + k * F_DIM + c1i);
        }
        f4 taf = __builtin_convertvector(*(const half4*)&T[bl][c0], f4);
        f4 tbf = __builtin_convertvector(*(const half4*)&T[bl][c1i], f4);

        float p[NLOC];
#pragma unroll
        for (int k = 0; k < NLOC; ++k) {
            f4 prod = la[k] * taf + lbv[k] * tbf;
            p[k] = prod[0] + prod[1] + prod[2] + prod[3];
        }
#pragma unroll
        for (int k = 0; k < NLOC; ++k) {
            float v = p[k];
            v += __shfl_xor(v, 1);
            v += __shfl_xor(v, 2);
            v += __shfl_xor(v, 4);
            v += __shfl_xor(v, 8);
            v += __shfl_xor(v, 16);
            v += __shfl_xor(v, 32);
            p[k] = v * 0.0625f;   // scale = 1/sqrt(256)
        }
        float mx = p[0];
#pragma unroll
        for (int k = 1; k < NLOC; ++k) mx = fmaxf(mx, p[k]);
        float e[NLOC], s = 0.f;
#pragma unroll
        for (int k = 0; k < NLOC; ++k) { e[k] = expf(p[k] - mx); s += e[k]; }
        const float inv = 1.f / s;

        f4 pA = {0.f,0.f,0.f,0.f}, pB = {0.f,0.f,0.f,0.f};
        f4 fA = {0.f,0.f,0.f,0.f}, fB = {0.f,0.f,0.f,0.f};
#pragma unroll
        for (int k = 0; k < NLOC; ++k) {
            const float ak = e[k] * inv;
            const float wk = wv[k];
            pA += ak * la[k]; pB += ak * lbv[k];
            fA += wk * la[k]; fB += wk * lbv[k];
        }
        half4 gA = *(const half4*)&G[bl][c0];
        half4 gB = *(const half4*)&G[bl][c1i];
        fA += bd + __builtin_convertvector(gA, f4);
        fB += bd + __builtin_convertvector(gB, f4);

        *(half4*)(Acat + b * 1024 + c0)          = __builtin_convertvector(pA, half4);
        *(half4*)(Acat + b * 1024 + c1i)         = __builtin_convertvector(pB, half4);
        *(half4*)(base + b * F_DIM + c0)         = __builtin_convertvector(fA, half4);
        *(half4*)(base + b * F_DIM + c1i)        = __builtin_convertvector(fB, half4);
    }
}

// ---------------------------------------------------------------------------
// K2: out = relu(Acat @ W2^T + cvec) + base.  M=16384, N=512, K=1024.
// v2: B-fragments direct from W2 (L2-resident, 1 MB), As double-buffered ->
//     one barrier per k-step. Block tile 64x128, 4 waves 2x2, wave 32x64.
// ---------------------------------------------------------------------------
__global__ void __launch_bounds__(256, 3) gemm_final(
    const _Float16* __restrict__ A, const _Float16* __restrict__ Bt,
    const float* __restrict__ cvec, const _Float16* __restrict__ base,
    float* __restrict__ out)
{
    __shared__ _Float16 As[2][64][40];
    const int tid = threadIdx.x;
    const int lane = tid & 63;
    const int wave = tid >> 6;
    const int quad = lane >> 4;
    const int l16 = lane & 15;
    const int wm = (wave & 1) * 32;
    const int wn = (wave >> 1) * 64;
    const long m0 = (long)blockIdx.x * 64;
    const int n0 = blockIdx.y * 128;
    const int srA = tid >> 2, scA = (tid & 3) * 8;

    const _Float16* bp0 = Bt + (long)(n0 + wn + l16) * 1024 + quad * 8;
    const _Float16* bp1 = bp0 + 16 * 1024;
    const _Float16* bp2 = bp0 + 32 * 1024;
    const _Float16* bp3 = bp0 + 48 * 1024;
    const _Float16* ap  = A + (m0 + srA) * 1024 + scA;

    f4 acc[2][4];
#pragma unroll
    for (int mi = 0; mi < 2; ++mi)
#pragma unroll
        for (int nj = 0; nj < 4; ++nj) acc[mi][nj] = (f4){0.f,0.f,0.f,0.f};

    // prologue: stage k-tile 0
    *(uint4*)&As[0][srA][scA] = *(const uint4*)(ap);
    __syncthreads();

#pragma unroll
    for (int kt = 0; kt < 32; ++kt) {
        const int k0 = kt * 32;
        uint4 avn;
        if (kt < 31) avn = *(const uint4*)(ap + k0 + 32);
        half8 b0 = *(const half8*)(bp0 + k0);
        half8 b1 = *(const half8*)(bp1 + k0);
        half8 b2 = *(const half8*)(bp2 + k0);
        half8 b3 = *(const half8*)(bp3 + k0);
        half8 a0 = *(const half8*)&As[kt & 1][wm + l16][quad * 8];
        half8 a1 = *(const half8*)&As[kt & 1][wm + 16 + l16][quad * 8];
        acc[0][0] = __builtin_amdgcn_mfma_f32_16x16x32_f16(a0, b0, acc[0][0], 0, 0, 0);
        acc[1][0] = __builtin_amdgcn_mfma_f32_16x16x32_f16(a1, b0, acc[1][0], 0, 0, 0);
        acc[0][1] = __builtin_amdgcn_mfma_f32_16x16x32_f16(a0, b1, acc[0][1], 0, 0, 0);
        acc[1][1] = __builtin_amdgcn_mfma_f32_16x16x32_f16(a1, b1, acc[1][1], 0, 0, 0);
        acc[0][2] = __builtin_amdgcn_mfma_f32_16x16x32_f16(a0, b2, acc[0][2], 0, 0, 0);
        acc[1][2] = __builtin_amdgcn_mfma_f32_16x16x32_f16(a1, b2, acc[1][2], 0, 0, 0);
        acc[0][3] = __builtin_amdgcn_mfma_f32_16x16x32_f16(a0, b3, acc[0][3], 0, 0, 0);
        acc[1][3] = __builtin_amdgcn_mfma_f32_16x16x32_f16(a1, b3, acc[1][3], 0, 0, 0);
        if (kt < 31) *(uint4*)&As[(kt & 1) ^ 1][srA][scA] = avn;
        __syncthreads();
    }

#pragma unroll
    for (int mi = 0; mi < 2; ++mi)
#pragma unroll
        for (int nj = 0; nj < 4; ++nj) {
            const int col = n0 + wn + nj * 16 + l16;
            const float cv = cvec[col];
#pragma unroll
            for (int i = 0; i < 4; ++i) {
                const long row = m0 + wm + mi * 16 + quad * 4 + i;
                float v = acc[mi][nj][i] + cv;
                v = fmaxf(v, 0.f) + (float)base[row * F_DIM + col];
                out[row * F_DIM + col] = v;
            }
        }
}

// ---------------------------------------------------------------------------
extern "C" void kernel_launch(void* const* d_in, const int* in_sizes, int n_in,
                              void* d_out, int out_size, void* d_ws, size_t ws_size,
                              hipStream_t stream)
{
    (void)in_sizes; (void)n_in; (void)out_size; (void)ws_size;
    const float* gf  = (const float*)d_in[0];
    const float* loc = (const float*)d_in[1];
    const float* Wq  = (const float*)d_in[2];
    const float* bq  = (const float*)d_in[3];
    const float* Wk  = (const float*)d_in[4];
    // d_in[5] = bk: dropped — contributes only a k-constant to s2 (softmax-invariant)
    const float* Wv  = (const float*)d_in[6];
    const float* bv  = (const float*)d_in[7];
    const float* wdr = (const float*)d_in[8];
    const float* bdr = (const float*)d_in[9];
    const float* Wf  = (const float*)d_in[10];
    const float* bfv = (const float*)d_in[11];
    float* out = (float*)d_out;

    char* ws = (char*)d_ws;
    _Float16* W1   = (_Float16*)(ws + OFF_W1);
    _Float16* W2   = (_Float16*)(ws + OFF_W2);
    float*    c1   = (float*)(ws + OFF_C1);
    float*    cvec = (float*)(ws + OFF_CVEC);
    _Float16* Acat = (_Float16*)(ws + OFF_ACAT);
    _Float16* base = (_Float16*)(ws + OFF_BASE);

    precompute_w<<<dim3(16, 16, 3), 256, 0, stream>>>(Wq, Wk, Wv, Wf, wdr, W1, W2);
    cvec_kernel<<<2, 256, 0, stream>>>(Wk, Wf, bq, bv, wdr, bdr, bfv, c1, cvec);
    fused_local<<<512, 256, 0, stream>>>(gf, loc, W1, c1, wdr, bdr, Acat, base);
    gemm_final<<<dim3(256, 4), 256, 0, stream>>>(Acat, W2, cvec, base, out);
}

// Round 2
// 679.493 us; speedup vs baseline: 1.0592x; 1.0592x over previous
//
#include <hip/hip_runtime.h>

#define NLOC 12
#define F_DIM 512
#define H_DIM 256

typedef float f4 __attribute__((ext_vector_type(4)));
typedef _Float16 half4 __attribute__((ext_vector_type(4)));
typedef _Float16 half8 __attribute__((ext_vector_type(8)));

// workspace layout (bytes)
#define OFF_W1   0ul
#define OFF_W2   (OFF_W1 + 512ul*512*2)          // W1: [512][512] f16
#define OFF_C1   (OFF_W2 + 512ul*1024*2)         // W2: [512][1024] f16
#define OFF_CVEC (OFF_C1 + 2048ul)               // c1: [512] f32
#define OFF_ACAT (OFF_CVEC + 2048ul)             // cvec: [512] f32
#define OFF_BASE (OFF_ACAT + 16384ul*1024*2)     // Acat: [B][1024] f16 (pooled | g)
// base: [B][512] f16  (lfm + g)

// ---------------------------------------------------------------------------
// Precompute W1[f,f'] = sum_h Wk[f,h] Wq[f',h]   (mode 0)
//            W2[f,j]  = sum_h Wf[h,f] Wv[j,h]            (mode 1, cols 0..511)
//            W2[f,512+j] = S * sum_h Wf[256+h,f] Wv[j,h] (mode 2)
// mode 3 (2 active blocks): c1 / cvec vectors — merged so the former
// cvec_kernel's serial launch runs concurrently on otherwise-idle CUs.
// ---------------------------------------------------------------------------
__global__ void __launch_bounds__(256) precompute_w(
    const float* __restrict__ Wq, const float* __restrict__ Wk,
    const float* __restrict__ Wv, const float* __restrict__ Wf,
    const float* __restrict__ wdr, const float* __restrict__ bq,
    const float* __restrict__ bv, const float* __restrict__ bdr,
    const float* __restrict__ bfv,
    _Float16* __restrict__ W1, _Float16* __restrict__ W2,
    float* __restrict__ c1, float* __restrict__ cvec)
{
    const int mode = blockIdx.z;
    const int t = threadIdx.x;

    if (mode == 3) {
        if (blockIdx.y != 0 || blockIdx.x >= 2) return;
        const int f = blockIdx.x * 256 + t;   // 0..511
        f4 a = {0.f, 0.f, 0.f, 0.f};
        const f4* wk4 = (const f4*)(Wk + (long)f * H_DIM);
        const f4* bq4 = (const f4*)bq;
#pragma unroll 4
        for (int h4 = 0; h4 < H_DIM / 4; ++h4) a += wk4[h4] * bq4[h4];
        c1[f] = a[0] + a[1] + a[2] + a[3];

        float s1 = 0.f, s2 = 0.f, s3 = 0.f;
#pragma unroll 4
        for (int h = 0; h < H_DIM; ++h) {
            float w1v = Wf[h * F_DIM + f];
            float w2v = Wf[(H_DIM + h) * F_DIM + f];
            float bvh = bv[h];
            s1 += bvh * w1v; s2 += bvh * w2v; s3 += w2v;
        }
        float S = 0.f;
#pragma unroll
        for (int k = 0; k < NLOC; ++k) S += wdr[k];
        cvec[f] = s1 + S * s2 + bdr[0] * s3 + bfv[f];
        return;
    }

    __shared__ float X[32][264];
    __shared__ float Y[32][264];
    const int f0 = blockIdx.x * 32;
    const int j0 = blockIdx.y * 32;

    {
        const int r = t >> 3, cb = (t & 7) * 32;
        const float* ysrc = ((mode == 0) ? Wq : Wv) + (j0 + r) * H_DIM + cb;
#pragma unroll
        for (int u = 0; u < 32; u += 4)
            *(f4*)&Y[r][cb + u] = *(const f4*)(ysrc + u);
        if (mode == 0) {
            const float* xsrc = Wk + (f0 + r) * H_DIM + cb;
#pragma unroll
            for (int u = 0; u < 32; u += 4)
                *(f4*)&X[r][cb + u] = *(const f4*)(xsrc + u);
        }
    }
    if (mode != 0) {
        const int h = t;                       // 0..255
        const int hoff = (mode == 2) ? H_DIM : 0;
        const float* xsrc = Wf + (long)(h + hoff) * F_DIM + f0;
        f4 v[8];
#pragma unroll
        for (int u = 0; u < 8; ++u) v[u] = *(const f4*)(xsrc + u * 4);
#pragma unroll
        for (int r = 0; r < 32; ++r) X[r][h] = v[r >> 2][r & 3];
    }
    __syncthreads();

    const int fy = t >> 4, jx = t & 15;
    float a00 = 0.f, a01 = 0.f, a10 = 0.f, a11 = 0.f;
#pragma unroll 8
    for (int h = 0; h < H_DIM; ++h) {
        float x0 = X[fy][h], x1 = X[fy + 16][h];
        float y0 = Y[jx][h], y1 = Y[jx + 16][h];
        a00 += x0 * y0; a01 += x0 * y1; a10 += x1 * y0; a11 += x1 * y1;
    }
    if (mode == 2) {
        float S = 0.f;
#pragma unroll
        for (int k = 0; k < NLOC; ++k) S += wdr[k];
        a00 *= S; a01 *= S; a10 *= S; a11 *= S;
    }
    if (mode == 0) {
        W1[(f0 + fy) * F_DIM + (j0 + jx)]             = (_Float16)a00;
        W1[(f0 + fy) * F_DIM + (j0 + jx + 16)]        = (_Float16)a01;
        W1[(f0 + fy + 16) * F_DIM + (j0 + jx)]        = (_Float16)a10;
        W1[(f0 + fy + 16) * F_DIM + (j0 + jx + 16)]   = (_Float16)a11;
    } else {
        const long co = (mode == 2) ? F_DIM : 0;
        W2[(long)(f0 + fy) * 1024 + co + (j0 + jx)]           = (_Float16)a00;
        W2[(long)(f0 + fy) * 1024 + co + (j0 + jx + 16)]      = (_Float16)a01;
        W2[(long)(f0 + fy + 16) * 1024 + co + (j0 + jx)]      = (_Float16)a10;
        W2[(long)(f0 + fy + 16) * 1024 + co + (j0 + jx + 16)] = (_Float16)a11;
    }
}

// ---------------------------------------------------------------------------
// K1: fused  (g->f16) + (t = g@W1^T + c1) + local pass.
// v3: phase-2 half-row software pipeline — next row's la-half prefetched
//     during current row's compute (48 extra VGPR; occupancy unchanged,
//     LDS-capped at 2 blocks/CU). Row-0 la issued before the barrier.
// ---------------------------------------------------------------------------
__global__ void __launch_bounds__(256, 2) fused_local(
    const float* __restrict__ g, const float* __restrict__ loc,
    const _Float16* __restrict__ W1, const float* __restrict__ c1,
    const float* __restrict__ wdr, const float* __restrict__ bdr,
    _Float16* __restrict__ Acat, _Float16* __restrict__ base)
{
    __shared__ _Float16 G[32][520];
    __shared__ _Float16 T[32][520];
    const int tid = threadIdx.x;
    const int lane = tid & 63;
    const int wave = tid >> 6;
    const int quad = lane >> 4;
    const int l16 = lane & 15;
    const long m0 = (long)blockIdx.x * 32;

    // ---- stage G (f32 -> f16), coalesced; also emit Acat's g-half here
    {
        const int r = tid >> 3;          // 0..31
        const int cb = (tid & 7) * 8;
#pragma unroll
        for (int u = 0; u < 512; u += 64) {
            const float* src = g + (m0 + r) * F_DIM + cb + u;
            f4 v0 = *(const f4*)(src);
            f4 v1 = *(const f4*)(src + 4);
            half8 hv;
#pragma unroll
            for (int j = 0; j < 4; ++j) { hv[j] = (_Float16)v0[j]; hv[4 + j] = (_Float16)v1[j]; }
            *(half8*)&G[r][cb + u] = hv;
            *(half8*)(Acat + (m0 + r) * 1024 + 512 + cb + u) = hv;
        }
    }
    __syncthreads();

    // ---- phase 1: T = G @ W1^T + c1 (barrier-free k-loop, B direct from L2)
    const int wn1 = wave * 32;
    for (int nt = 0; nt < 4; ++nt) {
        const int n0 = nt * 128;
        const _Float16* wb0 = W1 + (long)(n0 + wn1 + l16) * F_DIM + quad * 8;
        const _Float16* wb1 = wb0 + 16 * F_DIM;
        f4 acc[2][2] = {{{0.f,0.f,0.f,0.f},{0.f,0.f,0.f,0.f}},
                        {{0.f,0.f,0.f,0.f},{0.f,0.f,0.f,0.f}}};
#pragma unroll
        for (int k0 = 0; k0 < 512; k0 += 32) {
            half8 b0 = *(const half8*)(wb0 + k0);
            half8 b1 = *(const half8*)(wb1 + k0);
            half8 a0 = *(const half8*)&G[l16][k0 + quad * 8];
            half8 a1 = *(const half8*)&G[16 + l16][k0 + quad * 8];
            acc[0][0] = __builtin_amdgcn_mfma_f32_16x16x32_f16(a0, b0, acc[0][0], 0, 0, 0);
            acc[0][1] = __builtin_amdgcn_mfma_f32_16x16x32_f16(a0, b1, acc[0][1], 0, 0, 0);
            acc[1][0] = __builtin_amdgcn_mfma_f32_16x16x32_f16(a1, b0, acc[1][0], 0, 0, 0);
            acc[1][1] = __builtin_amdgcn_mfma_f32_16x16x32_f16(a1, b1, acc[1][1], 0, 0, 0);
        }
#pragma unroll
        for (int ni = 0; ni < 2; ++ni) {
            const int col = n0 + wn1 + ni * 16 + l16;
            const float cv = c1[col];
#pragma unroll
            for (int mi = 0; mi < 2; ++mi)
#pragma unroll
                for (int i = 0; i < 4; ++i)
                    T[mi * 16 + quad * 4 + i][col] = (_Float16)(acc[mi][ni][i] + cv);
        }
    }

    // ---- phase 2: local pass, 8 rows per wave, half-row pipelined
    const int c0 = lane * 4;
    const int c1i = 256 + lane * 4;
    const float bd = bdr[0];
    float wv[NLOC];
#pragma unroll
    for (int k = 0; k < NLOC; ++k) wv[k] = wdr[k];

    f4 laA[NLOC], laB[NLOC];
    {
        const float* lb0 = loc + (m0 + wave * 8) * (NLOC * F_DIM);
#pragma unroll
        for (int k = 0; k < NLOC; ++k) laA[k] = *(const f4*)(lb0 + k * F_DIM + c0);
    }
    __syncthreads();   // T ready; row-0 la loads drain here too

    auto row_body = [&](int rr, f4 (&la)[NLOC], f4 (&laN)[NLOC]) {
        const int bl = wave * 8 + rr;
        const long b = m0 + bl;
        const float* lb = loc + b * (NLOC * F_DIM);

        f4 lbv[NLOC];
#pragma unroll
        for (int k = 0; k < NLOC; ++k)
            lbv[k] = *(const f4*)(lb + k * F_DIM + c1i);
        if (rr < 7) {
            const float* lbn = lb + NLOC * F_DIM;
#pragma unroll
            for (int k = 0; k < NLOC; ++k)
                laN[k] = *(const f4*)(lbn + k * F_DIM + c0);
        }

        f4 taf = __builtin_convertvector(*(const half4*)&T[bl][c0], f4);
        f4 tbf = __builtin_convertvector(*(const half4*)&T[bl][c1i], f4);

        float p[NLOC];
#pragma unroll
        for (int k = 0; k < NLOC; ++k) {
            f4 prod = la[k] * taf + lbv[k] * tbf;
            p[k] = prod[0] + prod[1] + prod[2] + prod[3];
        }
#pragma unroll
        for (int k = 0; k < NLOC; ++k) {
            float v = p[k];
            v += __shfl_xor(v, 1);
            v += __shfl_xor(v, 2);
            v += __shfl_xor(v, 4);
            v += __shfl_xor(v, 8);
            v += __shfl_xor(v, 16);
            v += __shfl_xor(v, 32);
            p[k] = v * 0.0625f;   // scale = 1/sqrt(256)
        }
        float mx = p[0];
#pragma unroll
        for (int k = 1; k < NLOC; ++k) mx = fmaxf(mx, p[k]);
        float e[NLOC], s = 0.f;
#pragma unroll
        for (int k = 0; k < NLOC; ++k) { e[k] = expf(p[k] - mx); s += e[k]; }
        const float inv = 1.f / s;

        f4 pA = {0.f,0.f,0.f,0.f}, pB = {0.f,0.f,0.f,0.f};
        f4 fA = {0.f,0.f,0.f,0.f}, fB = {0.f,0.f,0.f,0.f};
#pragma unroll
        for (int k = 0; k < NLOC; ++k) {
            const float ak = e[k] * inv;
            const float wk = wv[k];
            pA += ak * la[k]; pB += ak * lbv[k];
            fA += wk * la[k]; fB += wk * lbv[k];
        }
        half4 gA = *(const half4*)&G[bl][c0];
        half4 gB = *(const half4*)&G[bl][c1i];
        fA += bd + __builtin_convertvector(gA, f4);
        fB += bd + __builtin_convertvector(gB, f4);

        *(half4*)(Acat + b * 1024 + c0)          = __builtin_convertvector(pA, half4);
        *(half4*)(Acat + b * 1024 + c1i)         = __builtin_convertvector(pB, half4);
        *(half4*)(base + b * F_DIM + c0)         = __builtin_convertvector(fA, half4);
        *(half4*)(base + b * F_DIM + c1i)        = __builtin_convertvector(fB, half4);
    };

#pragma unroll
    for (int it = 0; it < 4; ++it) {
        row_body(it * 2,     laA, laB);
        row_body(it * 2 + 1, laB, laA);
    }
}

// ---------------------------------------------------------------------------
// K2: out = relu(Acat @ W2^T + cvec) + base.  M=16384, N=512, K=1024.
// v3: 128x128 block tile, A and B both LDS-staged (B L2 traffic halved vs
//     v2's per-wave direct loads), double-buffered, 1 barrier per k-step.
//     4 waves 2x2, each wave 64x64 (4x4 mfma 16x16x32). Grid (128,4).
// ---------------------------------------------------------------------------
__global__ void __launch_bounds__(256, 2) gemm_final(
    const _Float16* __restrict__ A, const _Float16* __restrict__ Bt,
    const float* __restrict__ cvec, const _Float16* __restrict__ base,
    float* __restrict__ out)
{
    __shared__ _Float16 As[2][128][40];
    __shared__ _Float16 Bs[2][128][40];
    const int tid = threadIdx.x;
    const int lane = tid & 63;
    const int wave = tid >> 6;
    const int quad = lane >> 4;
    const int l16 = lane & 15;
    const int wm = (wave & 1) * 64;
    const int wn = (wave >> 1) * 64;
    const long m0 = (long)blockIdx.x * 128;
    const int n0 = blockIdx.y * 128;
    const int sr = tid >> 1, sc = (tid & 1) * 16;

    const _Float16* ap = A  + (m0 + sr) * 1024 + sc;
    const _Float16* bp = Bt + (long)(n0 + sr) * 1024 + sc;

    f4 acc[4][4];
#pragma unroll
    for (int mi = 0; mi < 4; ++mi)
#pragma unroll
        for (int nj = 0; nj < 4; ++nj) acc[mi][nj] = (f4){0.f,0.f,0.f,0.f};

    // prologue: stage k-tile 0
    {
        uint4 a0 = *(const uint4*)(ap);
        uint4 a1 = *(const uint4*)(ap + 8);
        uint4 b0 = *(const uint4*)(bp);
        uint4 b1 = *(const uint4*)(bp + 8);
        *(uint4*)&As[0][sr][sc]     = a0;
        *(uint4*)&As[0][sr][sc + 8] = a1;
        *(uint4*)&Bs[0][sr][sc]     = b0;
        *(uint4*)&Bs[0][sr][sc + 8] = b1;
    }
    __syncthreads();

#pragma unroll 4
    for (int kt = 0; kt < 32; ++kt) {
        const int cur = kt & 1;
        uint4 a0, a1, b0, b1;
        if (kt < 31) {
            const int k0 = (kt + 1) * 32;
            a0 = *(const uint4*)(ap + k0);
            a1 = *(const uint4*)(ap + k0 + 8);
            b0 = *(const uint4*)(bp + k0);
            b1 = *(const uint4*)(bp + k0 + 8);
        }
        half8 af[4], bf[4];
#pragma unroll
        for (int i = 0; i < 4; ++i) {
            af[i] = *(const half8*)&As[cur][wm + i * 16 + l16][quad * 8];
            bf[i] = *(const half8*)&Bs[cur][wn + i * 16 + l16][quad * 8];
        }
#pragma unroll
        for (int mi = 0; mi < 4; ++mi)
#pragma unroll
            for (int nj = 0; nj < 4; ++nj)
                acc[mi][nj] = __builtin_amdgcn_mfma_f32_16x16x32_f16(af[mi], bf[nj], acc[mi][nj], 0, 0, 0);
        if (kt < 31) {
            *(uint4*)&As[cur ^ 1][sr][sc]     = a0;
            *(uint4*)&As[cur ^ 1][sr][sc + 8] = a1;
            *(uint4*)&Bs[cur ^ 1][sr][sc]     = b0;
            *(uint4*)&Bs[cur ^ 1][sr][sc + 8] = b1;
        }
        __syncthreads();
    }

#pragma unroll
    for (int mi = 0; mi < 4; ++mi)
#pragma unroll
        for (int nj = 0; nj < 4; ++nj) {
            const int col = n0 + wn + nj * 16 + l16;
            const float cv = cvec[col];
#pragma unroll
            for (int i = 0; i < 4; ++i) {
                const long row = m0 + wm + mi * 16 + quad * 4 + i;
                float v = acc[mi][nj][i] + cv;
                v = fmaxf(v, 0.f) + (float)base[row * F_DIM + col];
                out[row * F_DIM + col] = v;
            }
        }
}

// ---------------------------------------------------------------------------
extern "C" void kernel_launch(void* const* d_in, const int* in_sizes, int n_in,
                              void* d_out, int out_size, void* d_ws, size_t ws_size,
                              hipStream_t stream)
{
    (void)in_sizes; (void)n_in; (void)out_size; (void)ws_size;
    const float* gf  = (const float*)d_in[0];
    const float* loc = (const float*)d_in[1];
    const float* Wq  = (const float*)d_in[2];
    const float* bq  = (const float*)d_in[3];
    const float* Wk  = (const float*)d_in[4];
    // d_in[5] = bk: dropped — contributes only a k-constant to s2 (softmax-invariant)
    const float* Wv  = (const float*)d_in[6];
    const float* bv  = (const float*)d_in[7];
    const float* wdr = (const float*)d_in[8];
    const float* bdr = (const float*)d_in[9];
    const float* Wf  = (const float*)d_in[10];
    const float* bfv = (const float*)d_in[11];
    float* out = (float*)d_out;

    char* ws = (char*)d_ws;
    _Float16* W1   = (_Float16*)(ws + OFF_W1);
    _Float16* W2   = (_Float16*)(ws + OFF_W2);
    float*    c1   = (float*)(ws + OFF_C1);
    float*    cvec = (float*)(ws + OFF_CVEC);
    _Float16* Acat = (_Float16*)(ws + OFF_ACAT);
    _Float16* base = (_Float16*)(ws + OFF_BASE);

    precompute_w<<<dim3(16, 16, 4), 256, 0, stream>>>(
        Wq, Wk, Wv, Wf, wdr, bq, bv, bdr, bfv, W1, W2, c1, cvec);
    fused_local<<<512, 256, 0, stream>>>(gf, loc, W1, c1, wdr, bdr, Acat, base);
    gemm_final<<<dim3(128, 4), 256, 0, stream>>>(Acat, W2, cvec, base, out);
}